// Round 3
// baseline (1221.123 us; speedup 1.0000x reference)
//
#include <hip/hip_runtime.h>

// ---------------------------------------------------------------------------
// Capsule cell: conv0(1x1,64->64) -> conv1(k=9,64->512) -> squash(512) ->
// conv2(k=3x512 strided,->256) -> dynamic routing (3 iters) -> out [32,4096,16]
//
// fp32 baseline (no MFMA: CDNA4 has no fp32-input MFMA).
// Layouts:
//   h0  : [B][64][L]        (channel-major, rows contiguous for conv1 LDS tiles)
//   h1  : [B][L][512]       (position-major: squash + conv2 read 512 contiguous)
//   V   : [B][LN][N][256]   (o = csb*16+asb contiguous for routing)
//   w1t : [cb][g][512 co]   (pre-transposed so A-tiles stage contiguously)
//   w2t : [g][c][256 o]
// ---------------------------------------------------------------------------

#define LL    2048
#define KK    64
#define NCAP  8
#define CO1   512
#define G2K   9
#define CO2   256
#define G3K   3
#define BB    32
#define LNN   256

// ws offsets (bytes)
#define OFF_W1T 0u
#define OFF_W2T 1179648u            // 64*9*512*4
#define OFF_H0  2752512u            // + 3*512*256*4
#define OFF_H1  19529728u           // + 32*64*2048*4
#define OFF_V   153747456u          // + 32*2048*512*4
// end: 220856320 (~211 MB)

// ---------------- weight pre-transpose --------------------------------------
__global__ __launch_bounds__(256) void prep_kernel(
    const float* __restrict__ w1, const float* __restrict__ w2,
    float* __restrict__ w1t, float* __restrict__ w2t) {
  int idx = blockIdx.x * 256 + threadIdx.x;
  if (idx < CO1 * 64 * G2K) {            // w1t[cb][g][co] = w1[co][cb][g]
    int co = idx % CO1;
    int g  = (idx / CO1) % G2K;
    int cb = idx / (CO1 * G2K);
    w1t[idx] = w1[(co * 64 + cb) * G2K + g];
  } else {
    int j = idx - CO1 * 64 * G2K;
    if (j < G3K * 512 * CO2) {           // w2t[g][c][o] = w2[o][g][c]
      int o = j % CO2;
      int c = (j / CO2) % 512;
      int g = j / (CO2 * 512);
      w2t[j] = w2[(o * G3K + g) * 512 + c];
    }
  }
}

// ---------------- conv0: 1x1, x[B][64][L] -> h0[B][64][L] -------------------
__global__ __launch_bounds__(256) void conv0_kernel(
    const float* __restrict__ x, const float* __restrict__ w0,
    const float* __restrict__ b0, float* __restrict__ h0) {
  __shared__ __align__(16) float xt[64][128];
  __shared__ __align__(16) float w0t[64][68];   // [k][cb], pad 68
  int tid = threadIdx.x;
  int b = blockIdx.y;
  int l0 = blockIdx.x * 128;
  const float* xb = x + (size_t)b * KK * LL;
#pragma unroll
  for (int i = 0; i < 8; i++) {                 // 2048 float4
    int idx = i * 256 + tid;
    int k = idx >> 5, l4 = idx & 31;
    float4 v = *(const float4*)&xb[k * LL + l0 + l4 * 4];
    *(float4*)&xt[k][l4 * 4] = v;
  }
#pragma unroll
  for (int i = 0; i < 16; i++) {                // 4096 scalars, transpose
    int idx = i * 256 + tid;
    int cb = idx >> 6, k = idx & 63;
    w0t[k][cb] = w0[idx];
  }
  __syncthreads();
  int lc = tid & 31, rc = tid >> 5;             // l=lc*4, cb=rc*8
  float acc[8][4] = {};
  for (int k = 0; k < 64; k++) {
    float4 bv = *(const float4*)&xt[k][lc * 4];
    float4 a0 = *(const float4*)&w0t[k][rc * 8];
    float4 a1 = *(const float4*)&w0t[k][rc * 8 + 4];
    float a[8] = {a0.x, a0.y, a0.z, a0.w, a1.x, a1.y, a1.z, a1.w};
    float bb4[4] = {bv.x, bv.y, bv.z, bv.w};
#pragma unroll
    for (int i = 0; i < 8; i++)
#pragma unroll
      for (int j = 0; j < 4; j++) acc[i][j] += a[i] * bb4[j];
  }
#pragma unroll
  for (int i = 0; i < 8; i++) {
    float bias = b0[rc * 8 + i];
    float4 s = make_float4(acc[i][0] + bias, acc[i][1] + bias,
                           acc[i][2] + bias, acc[i][3] + bias);
    *(float4*)&h0[((size_t)b * 64 + rc * 8 + i) * LL + l0 + lc * 4] = s;
  }
}

// ---------------- conv1: k=9, h0 -> h1[B][L][512] ---------------------------
// block: 128 co x 128 l, thread 8x8.  K-loop: 16 chunks of 4 cb, g inner via
// 16-float register window (4 aligned b128 reads).
__global__ __launch_bounds__(256) void conv1_kernel(
    const float* __restrict__ h0, const float* __restrict__ w1t,
    const float* __restrict__ b1, float* __restrict__ h1) {
  __shared__ __align__(16) float Bt[64][136];      // [cb][col], col0 = l0-4
  __shared__ __align__(16) float At[4][9][128];    // [cbc][g][co]
  int tid = threadIdx.x;
  int b = blockIdx.z;
  int co0 = blockIdx.y * 128;
  int l0 = blockIdx.x * 128;
  const float* h0b = h0 + (size_t)b * 64 * LL;
#pragma unroll
  for (int i = 0; i < 34; i++) {                   // 8704 = 64*136
    int idx = i * 256 + tid;
    int row = idx / 136, col = idx % 136;
    int l = l0 - 4 + col;
    Bt[row][col] = (l >= 0 && l < LL) ? h0b[row * LL + l] : 0.f;
  }
  float acc[8][8] = {};
  int lc = tid & 15, rc = tid >> 4;                // l=lc*8.., co=rc*8..
  for (int cc = 0; cc < 16; cc++) {
#pragma unroll
    for (int i = 0; i < 5; i++) {                  // 1152 float4 = 4*9*128
      int idx = i * 256 + tid;
      if (idx < 1152) {
        int co4 = idx & 31;
        int g = (idx >> 5) % 9;
        int cbc = idx / 288;
        float4 v = *(const float4*)&w1t[((size_t)(cc * 4 + cbc) * 9 + g) * 512 + co0 + co4 * 4];
        *(float4*)&At[cbc][g][co4 * 4] = v;
      }
    }
    __syncthreads();
#pragma unroll
    for (int cbc = 0; cbc < 4; cbc++) {
      const float* bp = &Bt[cc * 4 + cbc][lc * 8];
      float4 t0 = *(const float4*)(bp);
      float4 t1 = *(const float4*)(bp + 4);
      float4 t2 = *(const float4*)(bp + 8);
      float4 t3 = *(const float4*)(bp + 12);
      float bwin[16] = {t0.x, t0.y, t0.z, t0.w, t1.x, t1.y, t1.z, t1.w,
                        t2.x, t2.y, t2.z, t2.w, t3.x, t3.y, t3.z, t3.w};
#pragma unroll
      for (int g = 0; g < 9; g++) {
        float4 a0 = *(const float4*)&At[cbc][g][rc * 8];
        float4 a1 = *(const float4*)&At[cbc][g][rc * 8 + 4];
        float a[8] = {a0.x, a0.y, a0.z, a0.w, a1.x, a1.y, a1.z, a1.w};
#pragma unroll
        for (int i = 0; i < 8; i++)
#pragma unroll
          for (int j = 0; j < 8; j++) acc[i][j] += a[i] * bwin[j + g];
      }
    }
    __syncthreads();
  }
  float bias[8];
#pragma unroll
  for (int i = 0; i < 8; i++) bias[i] = b1[co0 + rc * 8 + i];
#pragma unroll
  for (int j = 0; j < 8; j++) {
    int l = l0 + lc * 8 + j;
    float* p = h1 + ((size_t)b * LL + l) * CO1 + co0 + rc * 8;
    *(float4*)p = make_float4(acc[0][j] + bias[0], acc[1][j] + bias[1],
                              acc[2][j] + bias[2], acc[3][j] + bias[3]);
    *(float4*)(p + 4) = make_float4(acc[4][j] + bias[4], acc[5][j] + bias[5],
                                    acc[6][j] + bias[6], acc[7][j] + bias[7]);
  }
}

// ---------------- squash over 512 channels, in place ------------------------
__global__ __launch_bounds__(256) void squash1_kernel(float* __restrict__ h1) {
  int tid = threadIdx.x;
  int wave = tid >> 6, lane = tid & 63;
  size_t row = (size_t)blockIdx.x * 4 + wave;      // b*L + l
  float* p = h1 + row * CO1;
  float4 v0 = *(const float4*)(p + lane * 4);
  float4 v1 = *(const float4*)(p + 256 + lane * 4);
  float sq = v0.x * v0.x + v0.y * v0.y + v0.z * v0.z + v0.w * v0.w +
             v1.x * v1.x + v1.y * v1.y + v1.z * v1.z + v1.w * v1.w;
#pragma unroll
  for (int m = 1; m < 64; m <<= 1) sq += __shfl_xor(sq, m, 64);
  float s = sq / (1.f + sq) / sqrtf(sq + 1e-8f);
  v0.x *= s; v0.y *= s; v0.z *= s; v0.w *= s;
  v1.x *= s; v1.y *= s; v1.z *= s; v1.w *= s;
  *(float4*)(p + lane * 4) = v0;
  *(float4*)(p + 256 + lane * 4) = v1;
}

// ---------------- conv2: per (b,n) GEMM 256o x 256ln, K=3*512 ---------------
__global__ __launch_bounds__(256) void conv2_kernel(
    const float* __restrict__ hsq, const float* __restrict__ w2t,
    const float* __restrict__ b2, float* __restrict__ V) {
  __shared__ __align__(16) float Bt[16][132];      // [ci][col], col0 = ln0-1
  __shared__ __align__(16) float At[16][3][128];   // [ci][g][o]
  int tid = threadIdx.x;
  int bn = blockIdx.z;
  int b = bn >> 3, n = bn & 7;
  int o0 = blockIdx.y * 128;
  int ln0 = blockIdx.x * 128;
  const float* hb = hsq + (size_t)b * LL * CO1;
  float acc[8][8] = {};
  int lc = tid & 15, rc = tid >> 4;                // ln=lc*8.., o=rc*8..
  for (int cc = 0; cc < 32; cc++) {
    int c0 = cc * 16;
#pragma unroll
    for (int i = 0; i < 9; i++) {                  // 2080 = 130*16 scalars
      int idx = i * 256 + tid;
      if (idx < 2080) {
        int pos = idx >> 4, ci = idx & 15;
        int lnh = ln0 - 1 + pos;
        float v = 0.f;
        if (lnh >= 0 && lnh < LNN)
          v = hb[((size_t)(lnh * NCAP + n)) * CO1 + c0 + ci];
        Bt[ci][pos] = v;
      }
    }
#pragma unroll
    for (int i = 0; i < 6; i++) {                  // 1536 float4 = 16*3*128
      int idx = i * 256 + tid;
      int o4 = idx & 31;
      int g = (idx >> 5) % 3;
      int ci = idx / 96;
      float4 v = *(const float4*)&w2t[((size_t)g * 512 + c0 + ci) * CO2 + o0 + o4 * 4];
      *(float4*)&At[ci][g][o4 * 4] = v;
    }
    __syncthreads();
#pragma unroll
    for (int ci = 0; ci < 16; ci++) {
      const float* bp = &Bt[ci][lc * 8];
      float4 t0 = *(const float4*)(bp);
      float4 t1 = *(const float4*)(bp + 4);
      float4 t2 = *(const float4*)(bp + 8);
      float bwin[12] = {t0.x, t0.y, t0.z, t0.w, t1.x, t1.y,
                        t1.z, t1.w, t2.x, t2.y, t2.z, t2.w};
#pragma unroll
      for (int g = 0; g < 3; g++) {
        float4 a0 = *(const float4*)&At[ci][g][rc * 8];
        float4 a1 = *(const float4*)&At[ci][g][rc * 8 + 4];
        float a[8] = {a0.x, a0.y, a0.z, a0.w, a1.x, a1.y, a1.z, a1.w};
#pragma unroll
        for (int i = 0; i < 8; i++)
#pragma unroll
          for (int j = 0; j < 8; j++) acc[i][j] += a[i] * bwin[j + g];
      }
    }
    __syncthreads();
  }
  float bias[8];
#pragma unroll
  for (int i = 0; i < 8; i++) bias[i] = b2[o0 + rc * 8 + i];
#pragma unroll
  for (int j = 0; j < 8; j++) {
    int ln = ln0 + lc * 8 + j;
    float* p = V + (((size_t)b * LNN + ln) * NCAP + n) * CO2 + o0 + rc * 8;
    *(float4*)p = make_float4(acc[0][j] + bias[0], acc[1][j] + bias[1],
                              acc[2][j] + bias[2], acc[3][j] + bias[3]);
    *(float4*)(p + 4) = make_float4(acc[4][j] + bias[4], acc[5][j] + bias[5],
                                    acc[6][j] + bias[6], acc[7][j] + bias[7]);
  }
}

// ---------------- dynamic routing: one block per (b,ln) ---------------------
__global__ __launch_bounds__(256) void routing_kernel(
    const float* __restrict__ V, float* __restrict__ out) {
  __shared__ float Vs[8][16][17];
  __shared__ float blog[8][16];
  __shared__ float cbuf[8][16];
  __shared__ float vbuf[16][17];
  int tid = threadIdx.x;
  size_t base = (size_t)blockIdx.x * 2048;
#pragma unroll
  for (int i = 0; i < 8; i++) {
    int idx = i * 256 + tid;
    int nn = idx >> 8, r = idx & 255;
    Vs[nn][r >> 4][r & 15] = V[base + idx];
  }
  if (tid < 128) blog[tid >> 4][tid & 15] = 0.f;
  __syncthreads();
  int csb = tid >> 4, asb = tid & 15;
  for (int r = 0; r < 3; r++) {
    if (tid < 128) {                     // softmax over csb (lane%16 = csb)
      int nn = tid >> 4, cs = tid & 15;
      float xv = blog[nn][cs];
      float m = xv;
#pragma unroll
      for (int d = 1; d < 16; d <<= 1) m = fmaxf(m, __shfl_xor(m, d, 16));
      float e = expf(xv - m);
      float ssum = e;
#pragma unroll
      for (int d = 1; d < 16; d <<= 1) ssum += __shfl_xor(ssum, d, 16);
      cbuf[nn][cs] = e / ssum;
    }
    __syncthreads();
    float s = 0.f;                       // s[csb][asb] = sum_n c*V
#pragma unroll
    for (int q = 0; q < 8; q++) s += cbuf[q][csb] * Vs[q][csb][asb];
    float sq = s * s;                    // reduce over asb (lane%16 = asb)
#pragma unroll
    for (int d = 1; d < 16; d <<= 1) sq += __shfl_xor(sq, d, 16);
    float vv = s * (sq / (1.f + sq) / sqrtf(sq + 1e-8f));
    if (r < 2) {
      vbuf[csb][asb] = vv;
      __syncthreads();
      if (tid < 128) {                   // a[n][csb] = sum_asb V*v
        int nn = tid >> 4, cs = tid & 15;
        float a = 0.f;
#pragma unroll
        for (int q = 0; q < 16; q++) a += Vs[nn][cs][q] * vbuf[cs][q];
        blog[nn][cs] += a;
      }
      __syncthreads();
    } else {
      out[(size_t)blockIdx.x * 256 + tid] = vv;
    }
  }
}

extern "C" void kernel_launch(void* const* d_in, const int* in_sizes, int n_in,
                              void* d_out, int out_size, void* d_ws, size_t ws_size,
                              hipStream_t stream) {
  const float* x  = (const float*)d_in[0];
  const float* w0 = (const float*)d_in[1];
  const float* b0 = (const float*)d_in[2];
  const float* w1 = (const float*)d_in[3];
  const float* b1 = (const float*)d_in[4];
  const float* w2 = (const float*)d_in[5];
  const float* b2 = (const float*)d_in[6];
  float* out = (float*)d_out;
  char* ws = (char*)d_ws;
  float* w1t = (float*)(ws + OFF_W1T);
  float* w2t = (float*)(ws + OFF_W2T);
  float* h0  = (float*)(ws + OFF_H0);
  float* h1  = (float*)(ws + OFF_H1);
  float* Vb  = (float*)(ws + OFF_V);

  prep_kernel<<<2688, 256, 0, stream>>>(w1, w2, w1t, w2t);
  conv0_kernel<<<dim3(16, 32), 256, 0, stream>>>(x, w0, b0, h0);
  conv1_kernel<<<dim3(16, 4, 32), 256, 0, stream>>>(h0, w1t, b1, h1);
  squash1_kernel<<<16384, 256, 0, stream>>>(h1);
  conv2_kernel<<<dim3(2, 2, 256), 256, 0, stream>>>(h1, w2t, b2, Vb);
  routing_kernel<<<8192, 256, 0, stream>>>(Vb, out);
}

// Round 6
// 254.154 us; speedup vs baseline: 4.8047x; 4.8047x over previous
//
#include <hip/hip_runtime.h>

// ---------------------------------------------------------------------------
// Capsule cell, bf16-MFMA version.
//   conv0 (1x1, fp32 VALU)          -> h0t  bf16 [B][L][64]      (B-frag layout)
//   conv1 (k=9, MFMA 16x16x32 bf16) -> h1   fp32 [B][L][512]
//   squash                          -> h1sq bf16 [B][L][512]
//   conv2 (k=3x512, MFMA)           -> V    fp32 [B][LN][N][256]
//   routing (3 iters, fp32)         -> out  [B][LN*16][16]
// MFMA layouts (m89/m91-verified): A lane&15 = M-row, 8 contig k at (lane>>4)*8;
// B lane&15 = N-col, same k; D col = lane&15, row = (lane>>4)*4 + reg.
// LDS tiles padded to 72 shorts/row (144 B) -> 2-way bank aliasing (free).
// Fallback if absmax too high: hi/lo split bf16 (3-term MFMA) on same machinery.
// ---------------------------------------------------------------------------

#define LL    2048
#define NCAP  8
#define CO1   512
#define CO2   256
#define LNN   256

typedef __attribute__((ext_vector_type(8))) short bhalf8;   // 8 bf16 (4 VGPR)
typedef __attribute__((ext_vector_type(4))) float facc4;    // MFMA accumulator

#define MFMA16(a, b, c) __builtin_amdgcn_mfma_f32_16x16x32_bf16(a, b, c, 0, 0, 0)

__device__ inline unsigned short f2bf(float f) {   // round-to-nearest-even
  unsigned u = __float_as_uint(f);
  return (unsigned short)((u + 0x7FFFu + ((u >> 16) & 1u)) >> 16);
}

// ws offsets (bytes)
#define OFF_W1TB 0u            // 9*512*64 bf16      = 589824
#define OFF_W2B  589824u       // 256*3*512 bf16     = 786432
#define OFF_H0T  1376256u      // 32*2048*64 bf16    = 8388608
#define OFF_H1   9764864u      // 32*2048*512 fp32   = 134217728 ; V aliases this
#define OFF_H1SQ 143982592u    // 32*2048*512 bf16   = 67108864 -> end 211091456

// ---------------- prep: weights -> bf16, MFMA-A layouts ---------------------
// w1tb[g][co 512][cb 64] = bf16(w1[co][cb][g]);  w2b = bf16(w2) ([o][g][c])
__global__ __launch_bounds__(256) void prep_kernel(
    const float* __restrict__ w1, const float* __restrict__ w2,
    unsigned short* __restrict__ w1tb, unsigned short* __restrict__ w2b) {
  int idx = blockIdx.x * 256 + threadIdx.x;
  if (idx < 294912) {                    // 9*512*64
    int cb = idx & 63;
    int co = (idx >> 6) & 511;
    int g  = idx >> 15;
    w1tb[idx] = f2bf(w1[(co * 64 + cb) * 9 + g]);
  } else {
    int j = idx - 294912;
    if (j < 393216) w2b[j] = f2bf(w2[j]);
  }
}

// ---------------- conv0: 1x1, x[B][64][L] -> h0t bf16 [B][L][64] ------------
__global__ __launch_bounds__(256) void conv0_kernel(
    const float* __restrict__ x, const float* __restrict__ w0,
    const float* __restrict__ b0, unsigned short* __restrict__ h0t) {
  __shared__ __align__(16) float xt[64][128];
  __shared__ __align__(16) float w0t[64][68];
  int tid = threadIdx.x;
  int b = blockIdx.y;
  int l0 = blockIdx.x * 128;
  const float* xb = x + (size_t)b * 64 * LL;
#pragma unroll
  for (int i = 0; i < 8; i++) {
    int idx = i * 256 + tid;
    int k = idx >> 5, l4 = idx & 31;
    float4 v = *(const float4*)&xb[k * LL + l0 + l4 * 4];
    *(float4*)&xt[k][l4 * 4] = v;
  }
#pragma unroll
  for (int i = 0; i < 16; i++) {
    int idx = i * 256 + tid;
    int cb = idx >> 6, k = idx & 63;
    w0t[k][cb] = w0[idx];
  }
  __syncthreads();
  int lc = tid & 31, rc = tid >> 5;             // l=lc*4+j, cb=rc*8+i
  float acc[8][4] = {};
  for (int k = 0; k < 64; k++) {
    float4 bv = *(const float4*)&xt[k][lc * 4];
    float4 a0 = *(const float4*)&w0t[k][rc * 8];
    float4 a1 = *(const float4*)&w0t[k][rc * 8 + 4];
    float a[8] = {a0.x, a0.y, a0.z, a0.w, a1.x, a1.y, a1.z, a1.w};
    float bb4[4] = {bv.x, bv.y, bv.z, bv.w};
#pragma unroll
    for (int i = 0; i < 8; i++)
#pragma unroll
      for (int j = 0; j < 4; j++) acc[i][j] += a[i] * bb4[j];
  }
  float bias[8];
#pragma unroll
  for (int i = 0; i < 8; i++) bias[i] = b0[rc * 8 + i];
#pragma unroll
  for (int j = 0; j < 4; j++) {
    bhalf8 o;
#pragma unroll
    for (int i = 0; i < 8; i++) o[i] = (short)f2bf(acc[i][j] + bias[i]);
    *(bhalf8*)&h0t[((size_t)b * LL + l0 + lc * 4 + j) * 64 + rc * 8] = o;
  }
}

// ---------------- conv1: k=9, 64->512, MFMA ---------------------------------
// block 512 thr (8 waves, 4co x 2l), out-tile 256co x 128l.
__global__ __launch_bounds__(512) void conv1_mfma(
    const unsigned short* __restrict__ h0t, const unsigned short* __restrict__ w1tb,
    const float* __restrict__ b1, float* __restrict__ h1) {
  __shared__ __align__(16) unsigned short Xt[136 * 72];   // rows l0-4..l0+131, 64cb pad72
  __shared__ __align__(16) unsigned short Wg[256 * 72];   // [co][cb pad72], per tap g
  int tid = threadIdx.x;
  int b = blockIdx.z;
  int co0 = blockIdx.y * 256;
  int l0 = blockIdx.x * 128;
#pragma unroll
  for (int it = 0; it < 3; it++) {                        // 1088 short8 tasks
    int idx = it * 512 + tid;
    if (idx < 1088) {
      int row = idx >> 3, c8 = (idx & 7) * 8;
      int l = l0 - 4 + row;
      bhalf8 v = (bhalf8)0;
      if (l >= 0 && l < LL) v = *(const bhalf8*)&h0t[((size_t)b * LL + l) * 64 + c8];
      *(bhalf8*)&Xt[row * 72 + c8] = v;
    }
  }
  int wid = tid >> 6, lane = tid & 63;
  int wr = wid >> 1, wc = wid & 1;
  int r16 = lane & 15, k8 = lane >> 4;
  facc4 acc[4][4] = {};
  for (int g = 0; g < 9; g++) {
    __syncthreads();                                      // Wg reuse + (g=0) Xt ready
#pragma unroll
    for (int it = 0; it < 4; it++) {                      // 2048 short8 tasks
      int idx = it * 512 + tid;
      int row = idx >> 3, c8 = (idx & 7) * 8;
      *(bhalf8*)&Wg[row * 72 + c8] =
          *(const bhalf8*)&w1tb[((size_t)(g * 512 + co0 + row)) * 64 + c8];
    }
    __syncthreads();
#pragma unroll
    for (int ks = 0; ks < 2; ks++) {
      bhalf8 A[4], Bf[4];
#pragma unroll
      for (int mi = 0; mi < 4; mi++)
        A[mi] = *(const bhalf8*)&Wg[(wr * 64 + mi * 16 + r16) * 72 + ks * 32 + k8 * 8];
#pragma unroll
      for (int ni = 0; ni < 4; ni++)
        Bf[ni] = *(const bhalf8*)&Xt[(wc * 64 + ni * 16 + r16 + g) * 72 + ks * 32 + k8 * 8];
#pragma unroll
      for (int mi = 0; mi < 4; mi++)
#pragma unroll
        for (int ni = 0; ni < 4; ni++)
          acc[mi][ni] = MFMA16(A[mi], Bf[ni], acc[mi][ni]);
    }
  }
#pragma unroll
  for (int mi = 0; mi < 4; mi++) {
    int co_w = co0 + wr * 64 + mi * 16 + k8 * 4;
    float4 bias = *(const float4*)&b1[co_w];
#pragma unroll
    for (int ni = 0; ni < 4; ni++) {
      int l_w = l0 + wc * 64 + ni * 16 + r16;
      float* p = &h1[((size_t)b * LL + l_w) * CO1 + co_w];
      *(float4*)p = make_float4(acc[mi][ni][0] + bias.x, acc[mi][ni][1] + bias.y,
                                acc[mi][ni][2] + bias.z, acc[mi][ni][3] + bias.w);
    }
  }
}

// ---------------- squash: h1 fp32 -> h1sq bf16 ------------------------------
__global__ __launch_bounds__(256) void squash1_kernel(
    const float* __restrict__ h1, unsigned short* __restrict__ h1sq) {
  int tid = threadIdx.x;
  int wave = tid >> 6, lane = tid & 63;
  size_t row = (size_t)blockIdx.x * 4 + wave;      // b*L + l
  const float* p = h1 + row * CO1;
  float4 v0 = *(const float4*)(p + lane * 8);
  float4 v1 = *(const float4*)(p + lane * 8 + 4);
  float sq = v0.x * v0.x + v0.y * v0.y + v0.z * v0.z + v0.w * v0.w +
             v1.x * v1.x + v1.y * v1.y + v1.z * v1.z + v1.w * v1.w;
#pragma unroll
  for (int m = 1; m < 64; m <<= 1) sq += __shfl_xor(sq, m, 64);
  float s = sq / (1.f + sq) / sqrtf(sq + 1e-8f);
  bhalf8 o;
  o[0] = (short)f2bf(v0.x * s); o[1] = (short)f2bf(v0.y * s);
  o[2] = (short)f2bf(v0.z * s); o[3] = (short)f2bf(v0.w * s);
  o[4] = (short)f2bf(v1.x * s); o[5] = (short)f2bf(v1.y * s);
  o[6] = (short)f2bf(v1.z * s); o[7] = (short)f2bf(v1.w * s);
  *(bhalf8*)&h1sq[row * CO1 + lane * 8] = o;
}

// ---------------- conv2: k=3 over ln, K=3*512, MFMA -------------------------
// block 512 thr (8 waves, 4o x 2ln), out-tile 256o x 128ln per (b,n).
__global__ __launch_bounds__(512) void conv2_mfma(
    const unsigned short* __restrict__ h1sq, const unsigned short* __restrict__ w2b,
    const float* __restrict__ b2, float* __restrict__ V) {
  __shared__ __align__(16) unsigned short Hc[130 * 72];   // rows ln0-1..ln0+128, 64c pad72
  __shared__ __align__(16) unsigned short Wgc[256 * 72];  // [o][c-chunk pad72]
  int tid = threadIdx.x;
  int bn = blockIdx.z;
  int b = bn >> 3, n = bn & 7;
  int ln0 = blockIdx.x * 128;
  int wid = tid >> 6, lane = tid & 63;
  int wr = wid >> 1, wc = wid & 1;
  int r16 = lane & 15, k8 = lane >> 4;
  facc4 acc[4][4] = {};
  for (int cc = 0; cc < 8; cc++) {
    int c0 = cc * 64;
    __syncthreads();                                      // Hc reuse
#pragma unroll
    for (int it = 0; it < 3; it++) {                      // 1040 short8 tasks
      int idx = it * 512 + tid;
      if (idx < 1040) {
        int row = idx >> 3, c8 = (idx & 7) * 8;
        int ln = ln0 - 1 + row;
        bhalf8 v = (bhalf8)0;
        if (ln >= 0 && ln < LNN)
          v = *(const bhalf8*)&h1sq[((size_t)b * LL + ln * NCAP + n) * CO1 + c0 + c8];
        *(bhalf8*)&Hc[row * 72 + c8] = v;
      }
    }
    for (int g = 0; g < 3; g++) {
      __syncthreads();                                    // Wgc reuse (+Hc ready at g=0)
#pragma unroll
      for (int it = 0; it < 4; it++) {                    // 2048 short8 tasks
        int idx = it * 512 + tid;
        int row = idx >> 3, c8 = (idx & 7) * 8;
        *(bhalf8*)&Wgc[row * 72 + c8] =
            *(const bhalf8*)&w2b[((size_t)(row * 3 + g)) * CO1 + c0 + c8];
      }
      __syncthreads();
#pragma unroll
      for (int ks = 0; ks < 2; ks++) {
        bhalf8 A[4], Bf[4];
#pragma unroll
        for (int mi = 0; mi < 4; mi++)
          A[mi] = *(const bhalf8*)&Wgc[(wr * 64 + mi * 16 + r16) * 72 + ks * 32 + k8 * 8];
#pragma unroll
        for (int ni = 0; ni < 4; ni++)
          Bf[ni] = *(const bhalf8*)&Hc[(wc * 64 + ni * 16 + r16 + g) * 72 + ks * 32 + k8 * 8];
#pragma unroll
        for (int mi = 0; mi < 4; mi++)
#pragma unroll
          for (int ni = 0; ni < 4; ni++)
            acc[mi][ni] = MFMA16(A[mi], Bf[ni], acc[mi][ni]);
      }
    }
  }
#pragma unroll
  for (int mi = 0; mi < 4; mi++) {
    int o_w = wr * 64 + mi * 16 + k8 * 4;
    float4 bias = *(const float4*)&b2[o_w];
#pragma unroll
    for (int ni = 0; ni < 4; ni++) {
      int ln_w = ln0 + wc * 64 + ni * 16 + r16;
      float* p = &V[(((size_t)b * LNN + ln_w) * NCAP + n) * CO2 + o_w];
      *(float4*)p = make_float4(acc[mi][ni][0] + bias.x, acc[mi][ni][1] + bias.y,
                                acc[mi][ni][2] + bias.z, acc[mi][ni][3] + bias.w);
    }
  }
}

// ---------------- dynamic routing: one block per (b,ln) ---------------------
__global__ __launch_bounds__(256) void routing_kernel(
    const float* __restrict__ V, float* __restrict__ out) {
  __shared__ float Vs[8][16][17];
  __shared__ float blog[8][16];
  __shared__ float cbuf[8][16];
  __shared__ float vbuf[16][17];
  int tid = threadIdx.x;
  size_t base = (size_t)blockIdx.x * 2048;
#pragma unroll
  for (int i = 0; i < 8; i++) {
    int idx = i * 256 + tid;
    int nn = idx >> 8, r = idx & 255;
    Vs[nn][r >> 4][r & 15] = V[base + idx];
  }
  if (tid < 128) blog[tid >> 4][tid & 15] = 0.f;
  __syncthreads();
  int csb = tid >> 4, asb = tid & 15;
  for (int r = 0; r < 3; r++) {
    if (tid < 128) {                     // softmax over csb (lane%16 = csb)
      int nn = tid >> 4, cs = tid & 15;
      float xv = blog[nn][cs];
      float m = xv;
#pragma unroll
      for (int d = 1; d < 16; d <<= 1) m = fmaxf(m, __shfl_xor(m, d, 16));
      float e = expf(xv - m);
      float ssum = e;
#pragma unroll
      for (int d = 1; d < 16; d <<= 1) ssum += __shfl_xor(ssum, d, 16);
      cbuf[nn][cs] = e / ssum;
    }
    __syncthreads();
    float s = 0.f;                       // s[csb][asb] = sum_n c*V
#pragma unroll
    for (int q = 0; q < 8; q++) s += cbuf[q][csb] * Vs[q][csb][asb];
    float sq = s * s;                    // reduce over asb
#pragma unroll
    for (int d = 1; d < 16; d <<= 1) sq += __shfl_xor(sq, d, 16);
    float vv = s * (sq / (1.f + sq) / sqrtf(sq + 1e-8f));
    if (r < 2) {
      vbuf[csb][asb] = vv;
      __syncthreads();
      if (tid < 128) {                   // a[n][csb] = sum_asb V*v
        int nn = tid >> 4, cs = tid & 15;
        float a = 0.f;
#pragma unroll
        for (int q = 0; q < 16; q++) a += Vs[nn][cs][q] * vbuf[cs][q];
        blog[nn][cs] += a;
      }
      __syncthreads();
    } else {
      out[(size_t)blockIdx.x * 256 + tid] = vv;
    }
  }
}

extern "C" void kernel_launch(void* const* d_in, const int* in_sizes, int n_in,
                              void* d_out, int out_size, void* d_ws, size_t ws_size,
                              hipStream_t stream) {
  const float* x  = (const float*)d_in[0];
  const float* w0 = (const float*)d_in[1];
  const float* b0 = (const float*)d_in[2];
  const float* w1 = (const float*)d_in[3];
  const float* b1 = (const float*)d_in[4];
  const float* w2 = (const float*)d_in[5];
  const float* b2 = (const float*)d_in[6];
  float* out = (float*)d_out;
  char* ws = (char*)d_ws;
  unsigned short* w1tb = (unsigned short*)(ws + OFF_W1TB);
  unsigned short* w2b  = (unsigned short*)(ws + OFF_W2B);
  unsigned short* h0t  = (unsigned short*)(ws + OFF_H0T);
  float*          h1   = (float*)(ws + OFF_H1);
  unsigned short* h1sq = (unsigned short*)(ws + OFF_H1SQ);
  float*          Vb   = (float*)(ws + OFF_H1);   // aliases h1 (dead after squash)

  prep_kernel<<<2688, 256, 0, stream>>>(w1, w2, w1tb, w2b);
  conv0_kernel<<<dim3(16, 32), 256, 0, stream>>>(x, w0, b0, h0t);
  conv1_mfma<<<dim3(16, 2, 32), 512, 0, stream>>>(h0t, w1tb, b1, h1);
  squash1_kernel<<<16384, 256, 0, stream>>>(h1, h1sq);
  conv2_mfma<<<dim3(2, 1, 256), 512, 0, stream>>>(h1sq, w2b, b2, Vb);
  routing_kernel<<<8192, 256, 0, stream>>>(Vb, out);
}